// Round 4
// baseline (179.165 us; speedup 1.0000x reference)
//
#include <hip/hip_runtime.h>

// ============================================================================
// einsum('bcshw,ijkl->bklhw') has no shared labels => full factorization:
//   out[b, kl, hw] = S_x[b,hw] * S_C[kl]
//   S_x[b,h,w] = sum_{p1,p2,ch} x[b, p1*8+h, p2*8+w, ch]
//   S_C[kl]    = sum over 3072 rows of C viewed as [3072][1024]
//
// Round-4 structure: K1 is a PURE STREAMER (no LDS, no barriers — Round-3's
// K1 carried 34 KB LDS + 2 barriers per 96 KiB slab, capping residency at
// 4 blocks/CU and costing ~20 µs of epilogue serialization). Register
// partials are dumped raw; the verified LDS epilogue runs once per IMAGE in
// K2a (8x fewer executions, L2-hot input).
//
//   K1  reduce_partials: blocks 0..95 = C column partials (32 rows each).
//       blocks 96..1119 = x-slab partials -> xdump[slab][h][192] f4, coalesced.
//   K2a finalize_sums: blocks 0..127 = per-image epilogue -> sxf[128][64];
//       blocks 128..131 = C collapse -> scf[1024].
//   K2b expand_out: pure outer-product expand, float4 stores.
// ============================================================================

__global__ __launch_bounds__(192) void reduce_partials(
    const float4* __restrict__ x4,    // [128*256 rows][192 f4]
    const float4* __restrict__ C4,    // [3072 rows][256 f4]
    float*  __restrict__ cpart,       // [96][1024]
    float4* __restrict__ xdump)       // [1024 slabs][8 h][192 t] f4
{
    const int t   = threadIdx.x;
    const int blk = blockIdx.x;

    if (blk < 96) {
        // ---- C partial: rows blk*32 .. +32, coalesced f4 column sums ----
        const size_t r0 = (size_t)blk * 32;
        for (int c4 = t; c4 < 256; c4 += 192) {
            const float4* p = C4 + r0 * 256 + c4;
            float ax = 0, ay = 0, az = 0, aw = 0;
            float bx = 0, by = 0, bz = 0, bw = 0;
#pragma unroll
            for (int r = 0; r < 32; r += 2) {
                float4 v0 = p[0];
                float4 v1 = p[256];
                ax += v0.x; ay += v0.y; az += v0.z; aw += v0.w;
                bx += v1.x; by += v1.y; bz += v1.z; bw += v1.w;
                p += 512;
            }
            float4 s;
            s.x = ax + bx; s.y = ay + by; s.z = az + bz; s.w = aw + bw;
            ((float4*)cpart)[blk * 256 + c4] = s;
        }
        return;
    }

    // ---- x slab partial: image b, rows chunk*32 .. +32, pure streaming ----
    // Row = 192 f4. Thread t reads f4 #t of each row (positions 4t+e).
    // Rows grouped by h = y%8 so acc[] indexing is static.
    const int xb    = blk - 96;            // [0,1024)
    const int b     = xb >> 3;
    const int chunk = xb & 7;
    const float4* base = x4 + ((size_t)b * 256 + (size_t)chunk * 32) * 192 + t;

    float4 acc[8];
#pragma unroll
    for (int h = 0; h < 8; ++h) { acc[h].x = acc[h].y = acc[h].z = acc[h].w = 0.f; }

#pragma unroll
    for (int h = 0; h < 8; ++h) {
#pragma unroll
        for (int j = 0; j < 4; ++j) {      // rows chunk*32 + h + 8j, y%8 == h
            float4 v = base[(size_t)(h + 8 * j) * 192];
            acc[h].x += v.x; acc[h].y += v.y; acc[h].z += v.z; acc[h].w += v.w;
        }
    }

    // Lane-coalesced dump: [xb][h][t] f4 (threads contiguous per store).
    float4* dst = xdump + (size_t)xb * 8 * 192 + t;
#pragma unroll
    for (int h = 0; h < 8; ++h) dst[h * 192] = acc[h];
}

// K2a: blocks 0..127 — per-image finalize. Sum the 8 slabs' dumps in
// registers (64 coalesced f4 loads/thread), then the verified two-stage LDS
// epilogue -> sxf[b][64]. Blocks 128..131 — collapse cpart -> scf[1024].
__global__ __launch_bounds__(256) void finalize_sums(
    const float4* __restrict__ xdump,  // [1024][8][192] f4
    const float*  __restrict__ cpart,  // [96][1024]
    float* __restrict__ sxf,           // [128][64]
    float* __restrict__ scf)           // [1024]
{
    const int blk = blockIdx.x;
    const int t   = threadIdx.x;

    if (blk >= 128) {                      // ---- C collapse ----
        const int col = (blk - 128) * 256 + t;   // [0,1024)
        float s = 0.f;
#pragma unroll 8
        for (int g = 0; g < 96; ++g) s += cpart[g * 1024 + col];
        scf[col] = s;
        return;
    }

    // ---- x finalize for image b = blk ----
    __shared__ float4 ldsv[192][9];   // [t][h]; 9 spreads write banks
    __shared__ float  plane[8][193];  // [h][pos mod 192]

    if (t < 192) {
        float4 acc[8];
#pragma unroll
        for (int h = 0; h < 8; ++h) { acc[h].x = acc[h].y = acc[h].z = acc[h].w = 0.f; }
        const float4* src = xdump + (size_t)blk * 8 * 8 * 192 + t;
#pragma unroll
        for (int s = 0; s < 8; ++s)
#pragma unroll
            for (int h = 0; h < 8; ++h) {
                float4 v = src[(size_t)(s * 8 + h) * 192];
                acc[h].x += v.x; acc[h].y += v.y; acc[h].z += v.z; acc[h].w += v.w;
            }
#pragma unroll
        for (int h = 0; h < 8; ++h) ldsv[t][h] = acc[h];
    }
    __syncthreads();

    if (t < 192) {   // stage 2: fold 4 period-groups (4*48*4 = 768 ≡ 0 mod 24)
        const int h2  = t / 48;           // 0..3
        const int tau = t - h2 * 48;      // 0..47
#pragma unroll
        for (int k = 0; k < 2; ++k) {
            const int hh = h2 + 4 * k;
            float4 s0 = ldsv[tau      ][hh];
            float4 s1 = ldsv[tau +  48][hh];
            float4 s2 = ldsv[tau +  96][hh];
            float4 s3 = ldsv[tau + 144][hh];
            plane[hh][4 * tau + 0] = s0.x + s1.x + s2.x + s3.x;
            plane[hh][4 * tau + 1] = s0.y + s1.y + s2.y + s3.y;
            plane[hh][4 * tau + 2] = s0.z + s1.z + s2.z + s3.z;
            plane[hh][4 * tau + 3] = s0.w + s1.w + s2.w + s3.w;
        }
    }
    __syncthreads();

    if (t < 64) {   // bin (h,w): positions p = 24g + 3w + c, g<8, c<3
        const int h = t >> 3, w = t & 7;
        float s = 0.f;
#pragma unroll
        for (int g = 0; g < 8; ++g) {
            const float* pp = &plane[h][24 * g + 3 * w];
            s += pp[0] + pp[1] + pp[2];
        }
        sxf[blk * 64 + t] = s;   // bin == t == h*8+w
    }
}

// K2b: pure expand. grid (8, 128): block = (kl-chunk of 128, image b).
// Per block: 192 broadcast floats in, 2048 coalesced float4 stores out.
__global__ __launch_bounds__(256) void expand_out(
    const float* __restrict__ sxf,    // [128][64]
    const float* __restrict__ scf,    // [1024]
    float4* __restrict__ out4)        // [128][1024][16]
{
    const int t   = threadIdx.x;
    const int klc = blockIdx.x;   // [0,8)
    const int b   = blockIdx.y;   // [0,128)

    __shared__ float4 sxv[16];    // sx[b][0..63] as 16 f4
    __shared__ float  scl[128];   // sC[klc*128 .. +128]

    if (t < 16) {
        sxv[t] = ((const float4*)(sxf + b * 64))[t];
    } else if (t >= 64 && t < 192) {
        scl[t - 64] = scf[klc * 128 + (t - 64)];
    }
    __syncthreads();

    float4* ob = out4 + (size_t)b * 16384 + (size_t)klc * 2048;
#pragma unroll
    for (int k = 0; k < 8; ++k) {
        const int idx = k * 256 + t;        // [0,2048)
        const float4 v = sxv[idx & 15];     // LDS broadcast
        const float  s = scl[idx >> 4];
        float4 r;
        r.x = v.x * s; r.y = v.y * s; r.z = v.z * s; r.w = v.w * s;
        ob[idx] = r;
    }
}

extern "C" void kernel_launch(void* const* d_in, const int* in_sizes, int n_in,
                              void* d_out, int out_size, void* d_ws, size_t ws_size,
                              hipStream_t stream) {
    const float4* x4 = (const float4*)d_in[0];   // 128*256*256*3 floats
    const float4* C4 = (const float4*)d_in[1];   // 3072*1024 floats

    float*  cpart = (float*)d_ws;                         // 96*1024 floats
    float4* xdump = (float4*)(cpart + 96 * 1024);         // 1024*8*192 f4
    float*  sxf   = (float*)(xdump + (size_t)1024 * 8 * 192);  // 128*64
    float*  scf   = sxf + 128 * 64;                       // 1024

    reduce_partials<<<dim3(96 + 1024), 192, 0, stream>>>(x4, C4, cpart, xdump);
    finalize_sums<<<dim3(132),         256, 0, stream>>>(xdump, cpart, sxf, scf);
    expand_out<<<dim3(8, 128),         256, 0, stream>>>(sxf, scf, (float4*)d_out);
}

// Round 6
// 167.721 us; speedup vs baseline: 1.0682x; 1.0682x over previous
//
#include <hip/hip_runtime.h>

// ============================================================================
// einsum('bcshw,ijkl->bklhw') has no shared labels => full factorization:
//   out[b, kl, hw] = S_x[b,hw] * S_C[kl]
//   S_x[b,h,w] = sum_{p1,p2,ch} x[b, p1*8+h, p2*8+w, ch]
//   S_C[kl]    = sum over 3072 rows of C viewed as [3072][1024]
//
// Round-5b: attack the x-stream (measured ~2.3 TB/s in ALL prior structures;
// epilogue proven ~free by R4). Theory: 8xfloat4 accumulators (~68 VGPR)
// limited outstanding loads to ~8/thread. Now each block owns ONE (b, h%8)
// class (rows h, h+8, ..., h+248): single float4 accumulator per thread,
// tiny register state, all 32 nontemporal loads can stay in flight.
// Epilogue reduces 192 f4 -> 8 floats and writes sxf directly (no xpart).
// (R5 compile fix: nontemporal builtins need clang ext_vector, not
//  HIP_vector_type — cast at the call sites.)
//
//   K1 blocks 0..1023   : x class-sums -> sxf[128][64] directly
//      blocks 1024..1119: C column partials (32 rows each) -> cpart[96][1024]
//   K2 collapse_C (6 blocks): cpart -> scf[1024]
//   K3 expand_out: pure outer-product expand, nontemporal float4 stores.
// ============================================================================

typedef float nf4 __attribute__((ext_vector_type(4)));

__global__ __launch_bounds__(192, 3) void reduce_partials(
    const float4* __restrict__ x4,    // [128*256 rows][192 f4]
    const float4* __restrict__ C4,    // [3072 rows][256 f4]
    float*  __restrict__ cpart,       // [96][1024]
    float*  __restrict__ sxf)         // [128][64]
{
    const int t   = threadIdx.x;
    const int blk = blockIdx.x;

    if (blk >= 1024) {
        // ---- C partial: rows cb*32 .. +32, coalesced f4 column sums ----
        const int cb = blk - 1024;
        const size_t r0 = (size_t)cb * 32;
        for (int c4 = t; c4 < 256; c4 += 192) {
            const float4* p = C4 + r0 * 256 + c4;
            float ax = 0, ay = 0, az = 0, aw = 0;
            float bx = 0, by = 0, bz = 0, bw = 0;
#pragma unroll
            for (int r = 0; r < 32; r += 2) {
                float4 v0 = p[0];
                float4 v1 = p[256];
                ax += v0.x; ay += v0.y; az += v0.z; aw += v0.w;
                bx += v1.x; by += v1.y; bz += v1.z; bw += v1.w;
                p += 512;
            }
            float4 s;
            s.x = ax + bx; s.y = ay + by; s.z = az + bz; s.w = aw + bw;
            ((float4*)cpart)[cb * 256 + c4] = s;
        }
        return;
    }

    // ---- x class-sum: image b, h-class h, rows {h+8j}, j=0..31 ----
    // Thread t reads f4 #t of each row (floats 4t..4t+3). Single f4 acc:
    // component e accumulates fixed class m = (4t+e) mod 24 within fixed h.
    const int b = blk >> 3;
    const int h = blk & 7;
    const nf4* base = (const nf4*)(x4 + ((size_t)b * 256 + h) * 192 + t);

    nf4 acc = (nf4)(0.f);
#pragma unroll
    for (int j = 0; j < 32; ++j) {       // 32 independent nt loads, tiny state
        nf4 v = __builtin_nontemporal_load(&base[(size_t)j * 8 * 192]);
        acc += v;
    }

    // Epilogue (proven ~free): 192 f4 -> 24 classes -> 8 w-sums.
    __shared__ float4 arr[192];
    __shared__ float4 arr2[48];
    __shared__ float  cls[24];

    arr[t].x = acc.x; arr[t].y = acc.y; arr[t].z = acc.z; arr[t].w = acc.w;
    __syncthreads();

    if (t < 48) {      // fold stride-48 groups: (4(t+48g)+e)%24 == (4t+e)%24
        float4 a0 = arr[t], a1 = arr[t + 48], a2 = arr[t + 96], a3 = arr[t + 144];
        float4 s;
        s.x = a0.x + a1.x + a2.x + a3.x;
        s.y = a0.y + a1.y + a2.y + a3.y;
        s.z = a0.z + a1.z + a2.z + a3.z;
        s.w = a0.w + a1.w + a2.w + a3.w;
        arr2[t] = s;
    }
    __syncthreads();

    if (t < 6) {       // fold stride-6 groups: class m = 4t+e, m in [0,24)
        float4 s; s.x = s.y = s.z = s.w = 0.f;
#pragma unroll
        for (int g = 0; g < 8; ++g) {
            float4 v = arr2[t + 6 * g];
            s.x += v.x; s.y += v.y; s.z += v.z; s.w += v.w;
        }
        cls[4 * t + 0] = s.x;
        cls[4 * t + 1] = s.y;
        cls[4 * t + 2] = s.z;
        cls[4 * t + 3] = s.w;
    }
    __syncthreads();

    if (t < 8) {       // class m = 3w + c: sum channels -> S_x[b, h*8+w]
        sxf[b * 64 + h * 8 + t] = cls[3 * t] + cls[3 * t + 1] + cls[3 * t + 2];
    }
}

// K2: collapse C partials once. 6 blocks x 192 threads cover 1024 cols.
__global__ __launch_bounds__(192) void collapse_C(
    const float* __restrict__ cpart,   // [96][1024]
    float* __restrict__ scf)           // [1024]
{
    const int col = blockIdx.x * 192 + threadIdx.x;
    if (col < 1024) {
        float s = 0.f;
#pragma unroll 8
        for (int g = 0; g < 96; ++g) s += cpart[g * 1024 + col];
        scf[col] = s;
    }
}

// K3: pure expand. grid (8, 128): block = (kl-chunk of 128, image b).
// Per block: 192 broadcast floats in, 2048 nontemporal float4 stores out.
__global__ __launch_bounds__(256) void expand_out(
    const float* __restrict__ sxf,    // [128][64]
    const float* __restrict__ scf,    // [1024]
    float4* __restrict__ out4)        // [128][1024][16]
{
    const int t   = threadIdx.x;
    const int klc = blockIdx.x;   // [0,8)
    const int b   = blockIdx.y;   // [0,128)

    __shared__ float4 sxv[16];    // sx[b][0..63] as 16 f4
    __shared__ float  scl[128];   // sC[klc*128 .. +128]

    if (t < 16) {
        sxv[t] = ((const float4*)(sxf + b * 64))[t];
    } else if (t >= 64 && t < 192) {
        scl[t - 64] = scf[klc * 128 + (t - 64)];
    }
    __syncthreads();

    float4* ob = out4 + (size_t)b * 16384 + (size_t)klc * 2048;
#pragma unroll
    for (int k = 0; k < 8; ++k) {
        const int idx = k * 256 + t;        // [0,2048)
        const float4 v = sxv[idx & 15];     // LDS broadcast
        const float  s = scl[idx >> 4];
        nf4 r;
        r.x = v.x * s; r.y = v.y * s; r.z = v.z * s; r.w = v.w * s;
        __builtin_nontemporal_store(r, (nf4*)&ob[idx]);
    }
}

extern "C" void kernel_launch(void* const* d_in, const int* in_sizes, int n_in,
                              void* d_out, int out_size, void* d_ws, size_t ws_size,
                              hipStream_t stream) {
    const float4* x4 = (const float4*)d_in[0];   // 128*256*256*3 floats
    const float4* C4 = (const float4*)d_in[1];   // 3072*1024 floats

    float* cpart = (float*)d_ws;                  // 96*1024 floats
    float* sxf   = cpart + 96 * 1024;             // 128*64 floats
    float* scf   = sxf + 128 * 64;                // 1024 floats

    reduce_partials<<<dim3(1024 + 96), 192, 0, stream>>>(x4, C4, cpart, sxf);
    collapse_C<<<dim3(6),              192, 0, stream>>>(cpart, scf);
    expand_out<<<dim3(8, 128),         256, 0, stream>>>(sxf, scf, (float4*)d_out);
}